// Round 1
// baseline (1320.343 us; speedup 1.0000x reference)
//
#include <hip/hip_runtime.h>

#define NEG_SLOPE 0.2f

constexpr int NN = 50000;   // nodes
constexpr int EE = 800000;  // edges (before self loops)

static __host__ __device__ inline int cdiv(int a, int b) { return (a + b - 1) / b; }

// ---------------- degree + edge_attr sum per dst ----------------
__global__ void deg_attr_kernel(const int* __restrict__ dst,
                                const float* __restrict__ eattr,
                                float* __restrict__ attrsum,   // [N,8] (pre-zeroed)
                                float* __restrict__ deg,       // [N]   (pre-zeroed)
                                int E) {
    int t = blockIdx.x * blockDim.x + threadIdx.x;
    if (t >= E * 8) return;
    int e = t >> 3, k = t & 7;
    int d = dst[e];
    atomicAdd(&attrsum[d * 8 + k], eattr[t]);
    if (k == 0) atomicAdd(&deg[d], 1.0f);
}

// loop_attr[n][k] = attrsum[n][k] / max(deg[n],1)   (in place)
__global__ void loop_div_kernel(float* __restrict__ attr,
                                const float* __restrict__ deg, int n8) {
    int t = blockIdx.x * blockDim.x + threadIdx.x;
    if (t >= n8) return;
    attr[t] = attr[t] / fmaxf(deg[t >> 3], 1.0f);
}

// ---------------- node linear: xl = x@Wl+bl, xr = x@Wr+br ----------------
template <int K, int CT>
__global__ __launch_bounds__(256) void node_linear_kernel(
    const float* __restrict__ x,
    const float* __restrict__ Wl, const float* __restrict__ bl,
    const float* __restrict__ Wr, const float* __restrict__ br,
    float* __restrict__ xl, float* __restrict__ xr, int n) {
    constexpr int NPB = 256 / CT;
    __shared__ float Wls[K * CT];
    __shared__ float Wrs[K * CT];
    int tid = threadIdx.y * CT + threadIdx.x;
    for (int i = tid; i < K * CT; i += 256) { Wls[i] = Wl[i]; Wrs[i] = Wr[i]; }
    __syncthreads();
    int node = blockIdx.x * NPB + threadIdx.y;
    if (node >= n) return;
    int c = threadIdx.x;
    float aL = bl[c], aR = br[c];
    const float* xrow = x + (size_t)node * K;
    for (int k = 0; k < K; ++k) {
        float xv = xrow[k];
        aL = fmaf(xv, Wls[k * CT + c], aL);
        aR = fmaf(xv, Wrs[k * CT + c], aR);
    }
    xl[(size_t)node * CT + c] = aL;
    xr[(size_t)node * CT + c] = aR;
}

// ---------------- edge message + softmax-accumulate ----------------
// One edge handled by CT consecutive threads (CT = H*C, C-groups wave-aligned).
template <int H, int C, int EPB>
__global__ __launch_bounds__(H * C * EPB) void edge_kernel(
    const int* __restrict__ src, const int* __restrict__ dst,
    const float* __restrict__ eattr, const float* __restrict__ loop_attr,
    const float* __restrict__ xl, const float* __restrict__ xr,
    const float* __restrict__ We, const float* __restrict__ att,
    float* __restrict__ accum,   // [N, CT] zeroed
    float* __restrict__ denom,   // [N, H]  zeroed
    int E, int n) {
    constexpr int CT = H * C;
    __shared__ float Wes[8 * CT];
    __shared__ float atts[CT];
    int x = threadIdx.x;
    int tid = threadIdx.y * CT + x;
    for (int i = tid; i < 8 * CT; i += CT * EPB) Wes[i] = We[i];
    if (tid < CT) atts[tid] = att[tid];
    __syncthreads();
    int e = blockIdx.x * EPB + threadIdx.y;
    if (e >= E + n) return;
    int s, d;
    const float* ea;
    if (e < E) {
        s = src[e]; d = dst[e]; ea = eattr + (size_t)e * 8;
    } else {
        s = e - E; d = s; ea = loop_attr + (size_t)s * 8;
    }
    float ep = 0.f;
#pragma unroll
    for (int k = 0; k < 8; ++k) ep = fmaf(ea[k], Wes[k * CT + x], ep);
    float xls = xl[(size_t)s * CT + x];
    float m = xls + xr[(size_t)d * CT + x] + ep;
    float sv = m > 0.f ? m : NEG_SLOPE * m;
    float p = sv * atts[x];
    // reduce over the C channels of this head (C-aligned lane group)
#pragma unroll
    for (int off = C / 2; off > 0; off >>= 1) p += __shfl_xor(p, off);
    float w = __expf(p);
    atomicAdd(&accum[(size_t)d * CT + x], w * xls);
    if ((x & (C - 1)) == 0) atomicAdd(&denom[(size_t)d * H + (x / C)], w);
}

// ---------------- finalize: divide, bias, optional residual, optional relu ----
template <int H, int C, bool RELU, bool RES>
__global__ void finalize_kernel(const float* __restrict__ accum,
                                const float* __restrict__ denom,
                                const float* __restrict__ bias,
                                const float* __restrict__ hres,  // [N,32] if RES
                                const float* __restrict__ Rw,    // [32,CT] if RES
                                float* __restrict__ out, int n) {
    constexpr int CT = H * C;
    int t = blockIdx.x * blockDim.x + threadIdx.x;
    if (t >= n * CT) return;
    int node = t / CT, c = t % CT;
    float v = accum[t] / denom[(size_t)node * H + c / C] + bias[c];
    if (RES) {
        const float* hr = hres + (size_t)node * 32;
#pragma unroll
        for (int k = 0; k < 32; ++k) v = fmaf(hr[k], Rw[k * CT + c], v);
    }
    if (RELU) v = fmaxf(v, 0.f);
    out[t] = v;
}

extern "C" void kernel_launch(void* const* d_in, const int* in_sizes, int n_in,
                              void* d_out, int out_size, void* d_ws, size_t ws_size,
                              hipStream_t stream) {
    const float* x    = (const float*)d_in[0];
    const int* ei     = (const int*)d_in[1];
    const float* eatt = (const float*)d_in[2];
    const float* Wl1 = (const float*)d_in[3],  *bl1 = (const float*)d_in[4];
    const float* Wr1 = (const float*)d_in[5],  *br1 = (const float*)d_in[6];
    const float* We1 = (const float*)d_in[7],  *att1 = (const float*)d_in[8];
    const float* b1  = (const float*)d_in[9];
    const float* Wl2 = (const float*)d_in[10], *bl2 = (const float*)d_in[11];
    const float* Wr2 = (const float*)d_in[12], *br2 = (const float*)d_in[13];
    const float* We2 = (const float*)d_in[14], *att2 = (const float*)d_in[15];
    const float* b2  = (const float*)d_in[16], *Rw2 = (const float*)d_in[17];
    const float* Wl3 = (const float*)d_in[18], *bl3 = (const float*)d_in[19];
    const float* Wr3 = (const float*)d_in[20], *br3 = (const float*)d_in[21];
    const float* We3 = (const float*)d_in[22], *att3 = (const float*)d_in[23];
    const float* b3  = (const float*)d_in[24];

    const int* srcp = ei;
    const int* dstp = ei + EE;

    // workspace layout (floats)
    float* w = (float*)d_ws;
    size_t off = 0;
    float* loop_attr = w + off; off += (size_t)NN * 8;
    float* deg       = w + off; off += NN;
    float* xl        = w + off; off += (size_t)NN * 128;
    float* xr        = w + off; off += (size_t)NN * 128;
    float* accum     = w + off; off += (size_t)NN * 128;   // hB aliases accum
    float* denom     = w + off; off += (size_t)NN * 4;
    float* hA        = w + off; off += (size_t)NN * 32;
    float* hB        = accum;  // finalize L2 is element-wise in-place

    // ---- self-loop attrs ----
    hipMemsetAsync(loop_attr, 0, (size_t)NN * 8 * 4, stream);
    hipMemsetAsync(deg, 0, (size_t)NN * 4, stream);
    deg_attr_kernel<<<cdiv(EE * 8, 256), 256, 0, stream>>>(dstp, eatt, loop_attr, deg, EE);
    loop_div_kernel<<<cdiv(NN * 8, 256), 256, 0, stream>>>(loop_attr, deg, NN * 8);

    // ---- layer 1: IN=16, H=4, C=8, CT=32 ----
    node_linear_kernel<16, 32><<<cdiv(NN, 8), dim3(32, 8), 0, stream>>>(
        x, Wl1, bl1, Wr1, br1, xl, xr, NN);
    hipMemsetAsync(accum, 0, (size_t)NN * 32 * 4, stream);
    hipMemsetAsync(denom, 0, (size_t)NN * 4 * 4, stream);
    edge_kernel<4, 8, 8><<<cdiv(EE + NN, 8), dim3(32, 8), 0, stream>>>(
        srcp, dstp, eatt, loop_attr, xl, xr, We1, att1, accum, denom, EE, NN);
    finalize_kernel<4, 8, true, false><<<cdiv(NN * 32, 256), 256, 0, stream>>>(
        accum, denom, b1, nullptr, nullptr, hA, NN);

    // ---- layer 2: IN=32, H=4, C=32, CT=128, residual ----
    node_linear_kernel<32, 128><<<cdiv(NN, 2), dim3(128, 2), 0, stream>>>(
        hA, Wl2, bl2, Wr2, br2, xl, xr, NN);
    hipMemsetAsync(accum, 0, (size_t)NN * 128 * 4, stream);
    hipMemsetAsync(denom, 0, (size_t)NN * 4 * 4, stream);
    edge_kernel<4, 32, 2><<<cdiv(EE + NN, 2), dim3(128, 2), 0, stream>>>(
        srcp, dstp, eatt, loop_attr, xl, xr, We2, att2, accum, denom, EE, NN);
    finalize_kernel<4, 32, true, true><<<cdiv(NN * 128, 256), 256, 0, stream>>>(
        accum, denom, b2, hA, Rw2, hB, NN);

    // ---- layer 3: IN=128, H=1, C=32, CT=32 ----
    node_linear_kernel<128, 32><<<cdiv(NN, 8), dim3(32, 8), 0, stream>>>(
        hB, Wl3, bl3, Wr3, br3, xl, xr, NN);
    hipMemsetAsync(accum, 0, (size_t)NN * 32 * 4, stream);   // hB dead after node_linear L3
    hipMemsetAsync(denom, 0, (size_t)NN * 1 * 4, stream);
    edge_kernel<1, 32, 8><<<cdiv(EE + NN, 8), dim3(32, 8), 0, stream>>>(
        srcp, dstp, eatt, loop_attr, xl, xr, We3, att3, accum, denom, EE, NN);
    finalize_kernel<1, 32, false, false><<<cdiv(NN * 32, 256), 256, 0, stream>>>(
        accum, denom, b3, nullptr, nullptr, (float*)d_out, NN);
}

// Round 2
// 592.509 us; speedup vs baseline: 2.2284x; 2.2284x over previous
//
#include <hip/hip_runtime.h>

#define NEG_SLOPE 0.2f

constexpr int NN = 50000;   // nodes
constexpr int EE = 800000;  // edges (before self loops)

static __host__ __device__ inline int cdiv(int a, int b) { return (a + b - 1) / b; }

// ================= CSR build =================
// rowcnt[d] = #original edges into d (atomics, int, cheap)
__global__ void hist_kernel(const int* __restrict__ dst, int* __restrict__ rowcnt, int E) {
    int t = blockIdx.x * blockDim.x + threadIdx.x;
    if (t < E) atomicAdd(&rowcnt[dst[t]], 1);
}

// per-block inclusive scan of (cnt+1) [+1 = self loop]
__global__ void scan1_kernel(const int* __restrict__ cnt, int* __restrict__ local,
                             int* __restrict__ blocksum, int n) {
    __shared__ int s[256];
    int t = threadIdx.x, g = blockIdx.x * 256 + t;
    int v = (g < n) ? cnt[g] + 1 : 0;
    s[t] = v; __syncthreads();
    for (int off = 1; off < 256; off <<= 1) {
        int tv = (t >= off) ? s[t - off] : 0; __syncthreads();
        s[t] += tv; __syncthreads();
    }
    if (g < n) local[g] = s[t];
    if (t == 255) blocksum[blockIdx.x] = s[255];
}

// exclusive scan of block sums (nb <= 256), single block
__global__ void scan2_kernel(int* __restrict__ blocksum, int nb) {
    __shared__ int s[256];
    int t = threadIdx.x;
    int v = (t < nb) ? blocksum[t] : 0;
    s[t] = v; __syncthreads();
    for (int off = 1; off < 256; off <<= 1) {
        int tv = (t >= off) ? s[t - off] : 0; __syncthreads();
        s[t] += tv; __syncthreads();
    }
    if (t < nb) blocksum[t] = s[t] - v;   // exclusive
}

__global__ void scan3_kernel(const int* __restrict__ local, const int* __restrict__ blocksum,
                             const int* __restrict__ cnt, int* __restrict__ rowptr,
                             int* __restrict__ cursor, int n) {
    int g = blockIdx.x * 256 + threadIdx.x;
    if (g >= n) return;
    int incl = local[g] + blocksum[blockIdx.x];
    rowptr[g + 1] = incl;
    cursor[g] = incl - (cnt[g] + 1);
    if (g == 0) rowptr[0] = 0;
}

// scatter edges (and self loops) into CSR; eid >= E marks self loop
__global__ void scatter_kernel(const int* __restrict__ src, const int* __restrict__ dst,
                               int* __restrict__ cursor, int* __restrict__ csr_src,
                               int* __restrict__ csr_eid, int E, int n) {
    int t = blockIdx.x * blockDim.x + threadIdx.x;
    if (t < E) {
        int d = dst[t];
        int pos = atomicAdd(&cursor[d], 1);
        csr_src[pos] = src[t];
        csr_eid[pos] = t;
    } else if (t < E + n) {
        int d = t - E;
        int pos = atomicAdd(&cursor[d], 1);
        csr_src[pos] = d;
        csr_eid[pos] = t;
    }
}

// loop_attr[n] = mean of eattr over original incoming edges (one wave per node)
__global__ __launch_bounds__(256) void loop_attr_kernel(
    const int* __restrict__ rowptr, const int* __restrict__ csr_eid,
    const float* __restrict__ eattr, float* __restrict__ loop_attr, int n, int E) {
    int wave = (blockIdx.x * 256 + threadIdx.x) >> 6;
    int lane = threadIdx.x & 63;
    if (wave >= n) return;
    int beg = rowptr[wave], end = rowptr[wave + 1];
    int k = lane & 7, j0 = lane >> 3;       // 8 edges in parallel
    float s = 0.f;
    for (int j = beg + j0; j < end; j += 8) {
        int eid = csr_eid[j];
        if (eid < E) s += eattr[(size_t)eid * 8 + k];
    }
    s += __shfl_xor(s, 8); s += __shfl_xor(s, 16); s += __shfl_xor(s, 32);
    int cnt = end - beg - 1;
    if (lane < 8) loop_attr[(size_t)wave * 8 + lane] = s / fmaxf((float)cnt, 1.f);
}

// ================= node linear: xl = x@Wl+bl, xr = x@Wr+br =================
template <int K, int CT>
__global__ __launch_bounds__(256) void node_linear_kernel(
    const float* __restrict__ x,
    const float* __restrict__ Wl, const float* __restrict__ bl,
    const float* __restrict__ Wr, const float* __restrict__ br,
    float* __restrict__ xl, float* __restrict__ xr, int n) {
    constexpr int NPB = 256 / CT;
    __shared__ float Wls[K * CT];
    __shared__ float Wrs[K * CT];
    int tid = threadIdx.y * CT + threadIdx.x;
    for (int i = tid; i < K * CT; i += 256) { Wls[i] = Wl[i]; Wrs[i] = Wr[i]; }
    __syncthreads();
    int node = blockIdx.x * NPB + threadIdx.y;
    if (node >= n) return;
    int c = threadIdx.x;
    float aL = bl[c], aR = br[c];
    const float* xrow = x + (size_t)node * K;
    for (int k = 0; k < K; ++k) {
        float xv = xrow[k];
        aL = fmaf(xv, Wls[k * CT + c], aL);
        aR = fmaf(xv, Wrs[k * CT + c], aR);
    }
    xl[(size_t)node * CT + c] = aL;
    xr[(size_t)node * CT + c] = aR;
}

// ================= CSR aggregation, CT=128 (layer 2) =================
// One wave per node; lane l holds channels (2l, 2l+1); head = lane/16.
template <bool RELU, bool RES>
__global__ __launch_bounds__(256) void agg128_kernel(
    const int* __restrict__ rowptr, const int* __restrict__ csr_src,
    const int* __restrict__ csr_eid,
    const float* __restrict__ eattr, const float* __restrict__ loop_attr,
    const float* __restrict__ xl, const float* __restrict__ xr,
    const float* __restrict__ We,   // [8,128]
    const float* __restrict__ att,  // flat [128]
    const float* __restrict__ bias, // [128]
    const float* __restrict__ hres, // [N,32] if RES
    const float* __restrict__ Rw,   // [32,128] if RES
    float* __restrict__ out, int n, int E) {
    __shared__ float Wes[8 * 128];
    __shared__ float Rws[RES ? 32 * 128 : 1];
    int tid = threadIdx.x;
    for (int i = tid; i < 8 * 128; i += 256) Wes[i] = We[i];
    if (RES) for (int i = tid; i < 32 * 128; i += 256) Rws[i] = Rw[i];
    __syncthreads();
    int node = (blockIdx.x * 256 + tid) >> 6;
    int lane = tid & 63;
    if (node >= n) return;
    int c0 = 2 * lane, c1 = c0 + 1;
    int beg = rowptr[node], end = rowptr[node + 1];
    const float2 xrc = *(const float2*)&xr[(size_t)node * 128 + c0];
    float att0 = att[c0], att1 = att[c1];
    float num0 = 0.f, num1 = 0.f, den = 0.f;
    int j = beg;
    int s = 0, eid = 0;
    if (j < end) { s = csr_src[j]; eid = csr_eid[j]; }
    for (; j < end; ) {
        int sc = s, ec = eid;
        ++j;
        if (j < end) { s = csr_src[j]; eid = csr_eid[j]; }   // prefetch next
        const float* ea = (ec < E) ? eattr + (size_t)ec * 8
                                   : loop_attr + (size_t)(ec - E) * 8;
        float2 xls = *(const float2*)&xl[(size_t)sc * 128 + c0];
        float ep0 = 0.f, ep1 = 0.f;
#pragma unroll
        for (int k = 0; k < 8; ++k) {
            float eav = ea[k];
            ep0 = fmaf(eav, Wes[k * 128 + c0], ep0);
            ep1 = fmaf(eav, Wes[k * 128 + c1], ep1);
        }
        float m0 = xls.x + xrc.x + ep0;
        float m1 = xls.y + xrc.y + ep1;
        float s0 = m0 > 0.f ? m0 : NEG_SLOPE * m0;
        float s1 = m1 > 0.f ? m1 : NEG_SLOPE * m1;
        float p = fmaf(s0, att0, s1 * att1);
        p += __shfl_xor(p, 1); p += __shfl_xor(p, 2);
        p += __shfl_xor(p, 4); p += __shfl_xor(p, 8);   // 16-lane head group
        float w = __expf(p);
        num0 = fmaf(w, xls.x, num0);
        num1 = fmaf(w, xls.y, num1);
        den += w;
    }
    float inv = 1.f / den;
    float v0 = num0 * inv + bias[c0];
    float v1 = num1 * inv + bias[c1];
    if (RES) {
        float hr = hres[(size_t)node * 32 + (lane & 31)];
#pragma unroll
        for (int k = 0; k < 32; ++k) {
            float hv = __shfl(hr, k, 32);
            v0 = fmaf(hv, Rws[k * 128 + c0], v0);
            v1 = fmaf(hv, Rws[k * 128 + c1], v1);
        }
    }
    if (RELU) { v0 = fmaxf(v0, 0.f); v1 = fmaxf(v1, 0.f); }
    float2 o; o.x = v0; o.y = v1;
    *(float2*)&out[(size_t)node * 128 + c0] = o;
}

// ================= CSR aggregation, CT=32 (layers 1, 3) =================
// One wave per node; 2 edges per iteration (lane = sub*32 + c); HC = channels/head.
template <int HC, bool RELU>
__global__ __launch_bounds__(256) void agg32_kernel(
    const int* __restrict__ rowptr, const int* __restrict__ csr_src,
    const int* __restrict__ csr_eid,
    const float* __restrict__ eattr, const float* __restrict__ loop_attr,
    const float* __restrict__ xl, const float* __restrict__ xr,
    const float* __restrict__ We,   // [8,32]
    const float* __restrict__ att,  // flat [32]
    const float* __restrict__ bias, // [32]
    float* __restrict__ out, int n, int E) {
    __shared__ float Wes[8 * 32];
    int tid = threadIdx.x;
    if (tid < 8 * 32) Wes[tid] = We[tid];
    __syncthreads();
    int node = (blockIdx.x * 256 + tid) >> 6;
    int lane = tid & 63;
    if (node >= n) return;
    int c = lane & 31, sub = lane >> 5;
    int beg = rowptr[node], end = rowptr[node + 1];
    float xrc = xr[(size_t)node * 32 + c];
    float attc = att[c];
    float num = 0.f, den = 0.f;
    int j = beg + sub;
    int s = 0, eid = 0;
    if (j < end) { s = csr_src[j]; eid = csr_eid[j]; }
    for (; j < end; ) {
        int sc = s, ec = eid;
        j += 2;
        if (j < end) { s = csr_src[j]; eid = csr_eid[j]; }   // prefetch next
        const float* ea = (ec < E) ? eattr + (size_t)ec * 8
                                   : loop_attr + (size_t)(ec - E) * 8;
        float xls = xl[(size_t)sc * 32 + c];
        float ep = 0.f;
#pragma unroll
        for (int k = 0; k < 8; ++k) ep = fmaf(ea[k], Wes[k * 32 + c], ep);
        float m = xls + xrc + ep;
        float sv = m > 0.f ? m : NEG_SLOPE * m;
        float p = sv * attc;
#pragma unroll
        for (int off = HC / 2; off > 0; off >>= 1) p += __shfl_xor(p, off);
        float w = __expf(p);
        num = fmaf(w, xls, num);
        den += w;
    }
    // combine the two edge-subsets
    num += __shfl_xor(num, 32);
    den += __shfl_xor(den, 32);
    if (sub == 0) {
        float v = num / den + bias[c];
        if (RELU) v = fmaxf(v, 0.f);
        out[(size_t)node * 32 + c] = v;
    }
}

extern "C" void kernel_launch(void* const* d_in, const int* in_sizes, int n_in,
                              void* d_out, int out_size, void* d_ws, size_t ws_size,
                              hipStream_t stream) {
    const float* x    = (const float*)d_in[0];
    const int* ei     = (const int*)d_in[1];
    const float* eatt = (const float*)d_in[2];
    const float* Wl1 = (const float*)d_in[3],  *bl1 = (const float*)d_in[4];
    const float* Wr1 = (const float*)d_in[5],  *br1 = (const float*)d_in[6];
    const float* We1 = (const float*)d_in[7],  *att1 = (const float*)d_in[8];
    const float* b1  = (const float*)d_in[9];
    const float* Wl2 = (const float*)d_in[10], *bl2 = (const float*)d_in[11];
    const float* Wr2 = (const float*)d_in[12], *br2 = (const float*)d_in[13];
    const float* We2 = (const float*)d_in[14], *att2 = (const float*)d_in[15];
    const float* b2  = (const float*)d_in[16], *Rw2 = (const float*)d_in[17];
    const float* Wl3 = (const float*)d_in[18], *bl3 = (const float*)d_in[19];
    const float* Wr3 = (const float*)d_in[20], *br3 = (const float*)d_in[21];
    const float* We3 = (const float*)d_in[22], *att3 = (const float*)d_in[23];
    const float* b3  = (const float*)d_in[24];

    const int* srcp = ei;
    const int* dstp = ei + EE;

    // ---- workspace layout ----
    char* w = (char*)d_ws;
    size_t off = 0;
    auto alloc = [&](size_t bytes) { char* p = w + off; off += (bytes + 255) & ~size_t(255); return p; };
    int*   rowcnt    = (int*)alloc((size_t)NN * 4);
    int*   rowptr    = (int*)alloc((size_t)(NN + 1) * 4);
    int*   cursor    = (int*)alloc((size_t)NN * 4);
    int*   blocksum  = (int*)alloc(256 * 4);
    int*   local     = (int*)alloc((size_t)NN * 4);
    int*   csr_src   = (int*)alloc((size_t)(EE + NN) * 4);
    int*   csr_eid   = (int*)alloc((size_t)(EE + NN) * 4);
    float* loop_attr = (float*)alloc((size_t)NN * 8 * 4);
    float* xlbuf     = (float*)alloc((size_t)NN * 128 * 4);
    float* xrbuf     = (float*)alloc((size_t)NN * 128 * 4);
    float* hA        = (float*)alloc((size_t)NN * 32 * 4);
    // hB aliases xrbuf: agg128 reads xr[node] before writing hB[node] (same wave)
    float* hB  = xrbuf;
    float* xl3 = xlbuf;              // layer-3 xl/xr live in the xl region
    float* xr3 = xlbuf + (size_t)NN * 32;

    int nb = cdiv(NN, 256);

    // ---- CSR build ----
    hipMemsetAsync(rowcnt, 0, (size_t)NN * 4, stream);
    hist_kernel<<<cdiv(EE, 256), 256, 0, stream>>>(dstp, rowcnt, EE);
    scan1_kernel<<<nb, 256, 0, stream>>>(rowcnt, local, blocksum, NN);
    scan2_kernel<<<1, 256, 0, stream>>>(blocksum, nb);
    scan3_kernel<<<nb, 256, 0, stream>>>(local, blocksum, rowcnt, rowptr, cursor, NN);
    scatter_kernel<<<cdiv(EE + NN, 256), 256, 0, stream>>>(
        srcp, dstp, cursor, csr_src, csr_eid, EE, NN);
    loop_attr_kernel<<<cdiv(NN, 4), 256, 0, stream>>>(
        rowptr, csr_eid, eatt, loop_attr, NN, EE);

    // ---- layer 1: IN=16 -> H=4, C=8 (CT=32) ----
    node_linear_kernel<16, 32><<<cdiv(NN, 8), dim3(32, 8), 0, stream>>>(
        x, Wl1, bl1, Wr1, br1, xlbuf, xrbuf, NN);
    agg32_kernel<8, true><<<cdiv(NN, 4), 256, 0, stream>>>(
        rowptr, csr_src, csr_eid, eatt, loop_attr, xlbuf, xrbuf, We1, att1, b1, hA, NN, EE);

    // ---- layer 2: IN=32 -> H=4, C=32 (CT=128), residual ----
    node_linear_kernel<32, 128><<<cdiv(NN, 2), dim3(128, 2), 0, stream>>>(
        hA, Wl2, bl2, Wr2, br2, xlbuf, xrbuf, NN);
    agg128_kernel<true, true><<<cdiv(NN, 4), 256, 0, stream>>>(
        rowptr, csr_src, csr_eid, eatt, loop_attr, xlbuf, xrbuf, We2, att2, b2,
        hA, Rw2, hB, NN, EE);

    // ---- layer 3: IN=128 -> H=1, C=32 (CT=32) ----
    node_linear_kernel<128, 32><<<cdiv(NN, 8), dim3(32, 8), 0, stream>>>(
        hB, Wl3, bl3, Wr3, br3, xl3, xr3, NN);
    agg32_kernel<32, false><<<cdiv(NN, 4), 256, 0, stream>>>(
        rowptr, csr_src, csr_eid, eatt, loop_attr, xl3, xr3, We3, att3, b3,
        (float*)d_out, NN, EE);
}

// Round 3
// 542.317 us; speedup vs baseline: 2.4346x; 1.0926x over previous
//
#include <hip/hip_runtime.h>
#include <hip/hip_fp16.h>

#define NEG_SLOPE 0.2f

constexpr int NN = 50000;   // nodes
constexpr int EE = 800000;  // edges (before self loops)

static inline int cdiv(int a, int b) { return (a + b - 1) / b; }

// ================= CSR build =================
__global__ void hist_kernel(const int* __restrict__ dst, int* __restrict__ rowcnt, int E) {
    int t = blockIdx.x * blockDim.x + threadIdx.x;
    if (t < E) atomicAdd(&rowcnt[dst[t]], 1);
}

// per-block inclusive scan of (cnt+1) [+1 = self loop]
__global__ void scan1_kernel(const int* __restrict__ cnt, int* __restrict__ local,
                             int* __restrict__ blocksum, int n) {
    __shared__ int s[256];
    int t = threadIdx.x, g = blockIdx.x * 256 + t;
    int v = (g < n) ? cnt[g] + 1 : 0;
    s[t] = v; __syncthreads();
    for (int off = 1; off < 256; off <<= 1) {
        int tv = (t >= off) ? s[t - off] : 0; __syncthreads();
        s[t] += tv; __syncthreads();
    }
    if (g < n) local[g] = s[t];
    if (t == 255) blocksum[blockIdx.x] = s[255];
}

__global__ void scan2_kernel(int* __restrict__ blocksum, int nb) {
    __shared__ int s[256];
    int t = threadIdx.x;
    int v = (t < nb) ? blocksum[t] : 0;
    s[t] = v; __syncthreads();
    for (int off = 1; off < 256; off <<= 1) {
        int tv = (t >= off) ? s[t - off] : 0; __syncthreads();
        s[t] += tv; __syncthreads();
    }
    if (t < nb) blocksum[t] = s[t] - v;   // exclusive
}

// rowptr, cursor (starting past the reserved self-loop front slot), self-loop src
__global__ void scan3_kernel(const int* __restrict__ local, const int* __restrict__ blocksum,
                             const int* __restrict__ cnt, int* __restrict__ rowptr,
                             int* __restrict__ cursor, int* __restrict__ csr_src, int n) {
    int g = blockIdx.x * 256 + threadIdx.x;
    if (g >= n) return;
    int incl = local[g] + blocksum[blockIdx.x];
    rowptr[g + 1] = incl;
    int beg = incl - (cnt[g] + 1);
    cursor[g] = beg + 1;          // slot `beg` reserved for the self loop
    csr_src[beg] = g;             // self-loop source
    if (g == 0) rowptr[0] = 0;
}

// scatter edges into CSR; also converts edge_attr -> fp16 in CSR order
__global__ void scatter_kernel(const int* __restrict__ src, const int* __restrict__ dst,
                               const float* __restrict__ eattr,
                               int* __restrict__ cursor, int* __restrict__ csr_src,
                               __half* __restrict__ csr_sea, int E) {
    int t = blockIdx.x * blockDim.x + threadIdx.x;
    if (t >= E) return;
    int d = dst[t];
    int pos = atomicAdd(&cursor[d], 1);
    csr_src[pos] = src[t];
    const float4* ea4 = (const float4*)(eattr + (size_t)t * 8);
    float4 a = ea4[0], b = ea4[1];
    __half2 h0 = __floats2half2_rn(a.x, a.y);
    __half2 h1 = __floats2half2_rn(a.z, a.w);
    __half2 h2 = __floats2half2_rn(b.x, b.y);
    __half2 h3 = __floats2half2_rn(b.z, b.w);
    uint4 u;
    u.x = *(unsigned*)&h0; u.y = *(unsigned*)&h1;
    u.z = *(unsigned*)&h2; u.w = *(unsigned*)&h3;
    *(uint4*)(csr_sea + (size_t)pos * 8) = u;
}

// fill each row's front slot with the mean of its (original) edge attrs
__global__ __launch_bounds__(256) void loop_sea_kernel(const int* __restrict__ rowptr,
                                                       __half* __restrict__ csr_sea, int n) {
    int wave = (blockIdx.x * 256 + threadIdx.x) >> 6;
    int lane = threadIdx.x & 63;
    if (wave >= n) return;
    int beg = rowptr[wave], end = rowptr[wave + 1];
    int k = lane & 7, j0 = lane >> 3;       // 8 edges in parallel
    float s = 0.f;
    for (int j = beg + 1 + j0; j < end; j += 8)
        s += __half2float(csr_sea[(size_t)j * 8 + k]);
    s += __shfl_xor(s, 8); s += __shfl_xor(s, 16); s += __shfl_xor(s, 32);
    int cnt = end - beg - 1;
    if (lane < 8) csr_sea[(size_t)beg * 8 + k] = __float2half(s / fmaxf((float)cnt, 1.f));
}

// ================= node linear: xl = x@Wl+bl, xr = x@Wr+br (fp16 out) =========
template <int K, int CT>
__global__ __launch_bounds__(256) void node_linear_kernel(
    const float* __restrict__ x,
    const float* __restrict__ Wl, const float* __restrict__ bl,
    const float* __restrict__ Wr, const float* __restrict__ br,
    __half* __restrict__ xl, __half* __restrict__ xr, int n) {
    constexpr int NPB = 256 / CT;
    __shared__ float Wls[K * CT];
    __shared__ float Wrs[K * CT];
    int tid = threadIdx.y * CT + threadIdx.x;
    for (int i = tid; i < K * CT; i += 256) { Wls[i] = Wl[i]; Wrs[i] = Wr[i]; }
    __syncthreads();
    int node = blockIdx.x * NPB + threadIdx.y;
    if (node >= n) return;
    int c = threadIdx.x;
    float aL = bl[c], aR = br[c];
    const float* xrow = x + (size_t)node * K;
    for (int k = 0; k < K; ++k) {
        float xv = xrow[k];
        aL = fmaf(xv, Wls[k * CT + c], aL);
        aR = fmaf(xv, Wrs[k * CT + c], aR);
    }
    xl[(size_t)node * CT + c] = __float2half(aL);
    xr[(size_t)node * CT + c] = __float2half(aR);
}

static __device__ inline void unpack_sea(const __half* __restrict__ sea, size_t j, float (&ea)[8]) {
    uint4 u = *(const uint4*)(sea + j * 8);
    __half2 h0 = *(__half2*)&u.x, h1 = *(__half2*)&u.y;
    __half2 h2 = *(__half2*)&u.z, h3 = *(__half2*)&u.w;
    float2 f0 = __half22float2(h0), f1 = __half22float2(h1);
    float2 f2 = __half22float2(h2), f3 = __half22float2(h3);
    ea[0] = f0.x; ea[1] = f0.y; ea[2] = f1.x; ea[3] = f1.y;
    ea[4] = f2.x; ea[5] = f2.y; ea[6] = f3.x; ea[7] = f3.y;
}

// ================= CSR aggregation, CT=128 (layer 2) =================
// One wave per node; lane l holds channels (2l, 2l+1); head = lane/16.
template <bool RELU, bool RES>
__global__ __launch_bounds__(256) void agg128_kernel(
    const int* __restrict__ rowptr, const int* __restrict__ csr_src,
    const __half* __restrict__ csr_sea,
    const __half2* __restrict__ xl2, const __half2* __restrict__ xr2,
    const float* __restrict__ We,   // [8,128]
    const float* __restrict__ att,  // flat [128]
    const float* __restrict__ bias, // [128]
    const float* __restrict__ hres, // [N,32] if RES
    const float* __restrict__ Rw,   // [32,128] if RES
    float* __restrict__ out, int n) {
    __shared__ float Rws[RES ? 32 * 128 : 1];
    int tid = threadIdx.x;
    if (RES) {
        for (int i = tid; i < 32 * 128; i += 256) Rws[i] = Rw[i];
        __syncthreads();
    }
    int node = (blockIdx.x * 256 + tid) >> 6;
    int lane = tid & 63;
    if (node >= n) return;
    int c0 = 2 * lane, c1 = c0 + 1;
    float wec0[8], wec1[8];
#pragma unroll
    for (int k = 0; k < 8; ++k) { wec0[k] = We[k * 128 + c0]; wec1[k] = We[k * 128 + c1]; }
    float att0 = att[c0], att1 = att[c1];
    int beg = rowptr[node], end = rowptr[node + 1];
    float2 xrc = __half22float2(xr2[(size_t)node * 64 + lane]);
    float num0 = 0.f, num1 = 0.f, den = 0.f;
    int s = csr_src[beg];
    for (int j = beg; j < end; ) {
        int sc = s; size_t jj = j;
        ++j;
        if (j < end) s = csr_src[j];          // prefetch next src
        float ea[8];
        unpack_sea(csr_sea, jj, ea);
        float2 xls = __half22float2(xl2[(size_t)sc * 64 + lane]);
        float ep0 = 0.f, ep1 = 0.f;
#pragma unroll
        for (int k = 0; k < 8; ++k) {
            ep0 = fmaf(ea[k], wec0[k], ep0);
            ep1 = fmaf(ea[k], wec1[k], ep1);
        }
        float m0 = xls.x + xrc.x + ep0;
        float m1 = xls.y + xrc.y + ep1;
        float s0 = m0 > 0.f ? m0 : NEG_SLOPE * m0;
        float s1 = m1 > 0.f ? m1 : NEG_SLOPE * m1;
        float p = fmaf(s0, att0, s1 * att1);
        p += __shfl_xor(p, 1); p += __shfl_xor(p, 2);
        p += __shfl_xor(p, 4); p += __shfl_xor(p, 8);   // 16-lane head group
        float w = __expf(p);
        num0 = fmaf(w, xls.x, num0);
        num1 = fmaf(w, xls.y, num1);
        den += w;
    }
    float inv = 1.f / den;
    float v0 = num0 * inv + bias[c0];
    float v1 = num1 * inv + bias[c1];
    if (RES) {
        float hr = hres[(size_t)node * 32 + (lane & 31)];
#pragma unroll
        for (int k = 0; k < 32; ++k) {
            float hv = __shfl(hr, k, 32);
            v0 = fmaf(hv, Rws[k * 128 + c0], v0);
            v1 = fmaf(hv, Rws[k * 128 + c1], v1);
        }
    }
    if (RELU) { v0 = fmaxf(v0, 0.f); v1 = fmaxf(v1, 0.f); }
    float2 o; o.x = v0; o.y = v1;
    *(float2*)&out[(size_t)node * 128 + c0] = o;
}

// ================= CSR aggregation, CT=32 (layers 1, 3) =================
// One wave per node; 2 edges per iteration (lane = sub*32 + c); HC = channels/head.
template <int HC, bool RELU>
__global__ __launch_bounds__(256) void agg32_kernel(
    const int* __restrict__ rowptr, const int* __restrict__ csr_src,
    const __half* __restrict__ csr_sea,
    const __half* __restrict__ xl, const __half* __restrict__ xr,
    const float* __restrict__ We,   // [8,32]
    const float* __restrict__ att,  // flat [32]
    const float* __restrict__ bias, // [32]
    float* __restrict__ out, int n) {
    int tid = threadIdx.x;
    int node = (blockIdx.x * 256 + tid) >> 6;
    int lane = tid & 63;
    if (node >= n) return;
    int c = lane & 31, sub = lane >> 5;
    float wec[8];
#pragma unroll
    for (int k = 0; k < 8; ++k) wec[k] = We[k * 32 + c];
    float attc = att[c];
    int beg = rowptr[node], end = rowptr[node + 1];
    float xrc = __half2float(xr[(size_t)node * 32 + c]);
    float num = 0.f, den = 0.f;
    int j = beg + sub;
    int s = 0;
    if (j < end) s = csr_src[j];
    for (; j < end; ) {
        int sc = s; size_t jj = j;
        j += 2;
        if (j < end) s = csr_src[j];          // prefetch next src
        float ea[8];
        unpack_sea(csr_sea, jj, ea);
        float xls = __half2float(xl[(size_t)sc * 32 + c]);
        float ep = 0.f;
#pragma unroll
        for (int k = 0; k < 8; ++k) ep = fmaf(ea[k], wec[k], ep);
        float m = xls + xrc + ep;
        float sv = m > 0.f ? m : NEG_SLOPE * m;
        float p = sv * attc;
#pragma unroll
        for (int off = HC / 2; off > 0; off >>= 1) p += __shfl_xor(p, off);
        float w = __expf(p);
        num = fmaf(w, xls, num);
        den += w;
    }
    num += __shfl_xor(num, 32);
    den += __shfl_xor(den, 32);
    if (sub == 0) {
        float v = num / den + bias[c];
        if (RELU) v = fmaxf(v, 0.f);
        out[(size_t)node * 32 + c] = v;
    }
}

extern "C" void kernel_launch(void* const* d_in, const int* in_sizes, int n_in,
                              void* d_out, int out_size, void* d_ws, size_t ws_size,
                              hipStream_t stream) {
    const float* x    = (const float*)d_in[0];
    const int* ei     = (const int*)d_in[1];
    const float* eatt = (const float*)d_in[2];
    const float* Wl1 = (const float*)d_in[3],  *bl1 = (const float*)d_in[4];
    const float* Wr1 = (const float*)d_in[5],  *br1 = (const float*)d_in[6];
    const float* We1 = (const float*)d_in[7],  *att1 = (const float*)d_in[8];
    const float* b1  = (const float*)d_in[9];
    const float* Wl2 = (const float*)d_in[10], *bl2 = (const float*)d_in[11];
    const float* Wr2 = (const float*)d_in[12], *br2 = (const float*)d_in[13];
    const float* We2 = (const float*)d_in[14], *att2 = (const float*)d_in[15];
    const float* b2  = (const float*)d_in[16], *Rw2 = (const float*)d_in[17];
    const float* Wl3 = (const float*)d_in[18], *bl3 = (const float*)d_in[19];
    const float* Wr3 = (const float*)d_in[20], *br3 = (const float*)d_in[21];
    const float* We3 = (const float*)d_in[22], *att3 = (const float*)d_in[23];
    const float* b3  = (const float*)d_in[24];

    const int* srcp = ei;
    const int* dstp = ei + EE;

    // ---- workspace layout (~75 MB) ----
    char* w = (char*)d_ws;
    size_t off = 0;
    auto alloc = [&](size_t bytes) { char* p = w + off; off += (bytes + 255) & ~size_t(255); return p; };
    int*    rowcnt   = (int*)alloc((size_t)NN * 4);
    int*    rowptr   = (int*)alloc((size_t)(NN + 1) * 4);
    int*    cursor   = (int*)alloc((size_t)NN * 4);
    int*    blocksum = (int*)alloc(256 * 4);
    int*    local    = (int*)alloc((size_t)NN * 4);
    int*    csr_src  = (int*)alloc((size_t)(EE + NN) * 4);
    __half* csr_sea  = (__half*)alloc((size_t)(EE + NN) * 8 * 2);
    __half* xlbuf    = (__half*)alloc((size_t)NN * 128 * 2);
    __half* xrbuf    = (__half*)alloc((size_t)NN * 128 * 2);
    float*  hA       = (float*)alloc((size_t)NN * 32 * 4);
    float*  hB       = (float*)alloc((size_t)NN * 128 * 4);

    int nb = cdiv(NN, 256);

    // ---- CSR build (self-loop in front slot of each row) ----
    hipMemsetAsync(rowcnt, 0, (size_t)NN * 4, stream);
    hist_kernel<<<cdiv(EE, 256), 256, 0, stream>>>(dstp, rowcnt, EE);
    scan1_kernel<<<nb, 256, 0, stream>>>(rowcnt, local, blocksum, NN);
    scan2_kernel<<<1, 256, 0, stream>>>(blocksum, nb);
    scan3_kernel<<<nb, 256, 0, stream>>>(local, blocksum, rowcnt, rowptr, cursor, csr_src, NN);
    scatter_kernel<<<cdiv(EE, 256), 256, 0, stream>>>(
        srcp, dstp, eatt, cursor, csr_src, csr_sea, EE);
    loop_sea_kernel<<<cdiv(NN, 4), 256, 0, stream>>>(rowptr, csr_sea, NN);

    // ---- layer 1: IN=16 -> H=4, C=8 (CT=32) ----
    node_linear_kernel<16, 32><<<cdiv(NN, 8), dim3(32, 8), 0, stream>>>(
        x, Wl1, bl1, Wr1, br1, xlbuf, xrbuf, NN);
    agg32_kernel<8, true><<<cdiv(NN, 4), 256, 0, stream>>>(
        rowptr, csr_src, csr_sea, xlbuf, xrbuf, We1, att1, b1, hA, NN);

    // ---- layer 2: IN=32 -> H=4, C=32 (CT=128), residual ----
    node_linear_kernel<32, 128><<<cdiv(NN, 2), dim3(128, 2), 0, stream>>>(
        hA, Wl2, bl2, Wr2, br2, xlbuf, xrbuf, NN);
    agg128_kernel<true, true><<<cdiv(NN, 4), 256, 0, stream>>>(
        rowptr, csr_src, csr_sea, (const __half2*)xlbuf, (const __half2*)xrbuf,
        We2, att2, b2, hA, Rw2, hB, NN);

    // ---- layer 3: IN=128 -> H=1, C=32 (CT=32) ----
    node_linear_kernel<128, 32><<<cdiv(NN, 8), dim3(32, 8), 0, stream>>>(
        hB, Wl3, bl3, Wr3, br3, xlbuf, xrbuf, NN);
    agg32_kernel<32, false><<<cdiv(NN, 4), 256, 0, stream>>>(
        rowptr, csr_src, csr_sea, xlbuf, xrbuf, We3, att3, b3,
        (float*)d_out, NN);
}